// Round 1
// baseline (180.266 us; speedup 1.0000x reference)
//
#include <hip/hip_runtime.h>

#define N_TOTAL 16384
#define HALF    8192
#define FEAT    128
#define MARGIN  0.3f

typedef __attribute__((ext_vector_type(8))) short  short8v;   // 8 x bf16 (4 VGPRs)
typedef __attribute__((ext_vector_type(4))) float  float4v;   // 4 x f32 acc

__device__ __forceinline__ unsigned short f32_to_bf16_rne(float f) {
    unsigned u = __float_as_uint(f);
    u += 0x7FFFu + ((u >> 16) & 1u);
    return (unsigned short)(u >> 16);
}

// ---------------------------------------------------------------------------
// prep: fp32 -> bf16 convert, row norms of the bf16-rounded vectors,
//       init maxpos = -inf bits, minneg = +inf bits.
// ---------------------------------------------------------------------------
__global__ __launch_bounds__(128) void prep_kernel(
        const float* __restrict__ X, unsigned short* __restrict__ Xb,
        float* __restrict__ sq, int* __restrict__ maxpos, int* __restrict__ minneg) {
    const int r = blockIdx.x;
    const int t = threadIdx.x;
    float x = X[r * FEAT + t];
    unsigned short h = f32_to_bf16_rne(x);
    Xb[r * FEAT + t] = h;
    float xr = __uint_as_float((unsigned)h << 16);
    float p = xr * xr;
    #pragma unroll
    for (int m = 1; m < 64; m <<= 1) p += __shfl_xor(p, m, 64);
    __shared__ float partial[2];
    if ((t & 63) == 0) partial[t >> 6] = p;
    __syncthreads();
    if (t == 0) {
        sq[r] = partial[0] + partial[1];
        maxpos[r] = (int)0xFF800000u;   // -inf (any d2 >= 0 beats it via signed int max)
        minneg[r] = 0x7F800000;         // +inf
    }
}

// ---------------------------------------------------------------------------
// main: 128x128 tile of the 8192x8192 cross-modality block.
//   S[i][j] = dot(x_i, x_{8192+j}) via bf16 MFMA 16x16x32, K=128 in one LDS stage.
//   Fused epilogue: d2 = sqA+sqB-2*dot, label compare, row/col max/min
//   reductions, atomic merge into global maxpos/minneg (int-cast trick, d2>=0).
// LDS layout: row-major 128x128 bf16 (256 B rows) with 16B-chunk XOR swizzle
//   chunk' = chunk ^ (row & 7)   -> fragment ds_read_b128 is ~2-way (free),
//   keeps per-block LDS at 64 KB (2 blocks/CU).
// ---------------------------------------------------------------------------
__global__ __launch_bounds__(256, 2) void cross_kernel(
        const unsigned short* __restrict__ Xb, const float* __restrict__ sq,
        const int* __restrict__ targets,
        int* __restrict__ maxpos, int* __restrict__ minneg) {
    __shared__ unsigned short As[128 * 128];
    __shared__ unsigned short Bs[128 * 128];
    const int bm = blockIdx.x, bn = blockIdx.y;
    const int t  = threadIdx.x;

    // ---- stage A (rows bm*128..) and B (rows 8192+bn*128..): contiguous 32 KB each
    const unsigned short* Ag = Xb + (size_t)bm * 128 * FEAT;
    const unsigned short* Bg = Xb + (size_t)(HALF + bn * 128) * FEAT;
    #pragma unroll
    for (int p = 0; p < 8; ++p) {
        int idx = p * 256 + t;            // 16B chunk id, 0..2047
        int row = idx >> 4, ch = idx & 15;
        int sc  = ch ^ (row & 7);
        uint4 va = ((const uint4*)Ag)[idx];
        uint4 vb = ((const uint4*)Bg)[idx];
        *(uint4*)&As[row * 128 + sc * 8] = va;
        *(uint4*)&Bs[row * 128 + sc * 8] = vb;
    }
    __syncthreads();

    const int wave = t >> 6, lane = t & 63;
    const int q = lane >> 4, c = lane & 15;
    const int wr = (wave >> 1) * 64, wc = (wave & 1) * 64;

    // ---- MFMA: wave computes 64x64 quadrant as 4x4 grid of 16x16 tiles
    float4v acc[4][4] = {};
    #pragma unroll
    for (int kk = 0; kk < 4; ++kk) {      // 32 k-elems per step; chunk = kk*4 + q
        short8v af[4], bfr[4];
        #pragma unroll
        for (int ti = 0; ti < 4; ++ti) {
            int row = wr + ti * 16 + c;
            int sc  = (kk * 4 + q) ^ (row & 7);
            af[ti] = *(const short8v*)&As[row * 128 + sc * 8];
        }
        #pragma unroll
        for (int tj = 0; tj < 4; ++tj) {
            int row = wc + tj * 16 + c;
            int sc  = (kk * 4 + q) ^ (row & 7);
            bfr[tj] = *(const short8v*)&Bs[row * 128 + sc * 8];
        }
        #pragma unroll
        for (int ti = 0; ti < 4; ++ti)
            #pragma unroll
            for (int tj = 0; tj < 4; ++tj)
                acc[ti][tj] = __builtin_amdgcn_mfma_f32_16x16x32_bf16(
                    af[ti], bfr[tj], acc[ti][tj], 0, 0, 0);
    }

    // ---- epilogue: C layout col = lane&15 (=c), row = q*4 + reg
    const float NEG_INF = __int_as_float((int)0xFF800000u);
    const float POS_INF = __int_as_float(0x7F800000);

    float sA[16]; int tA[16];
    #pragma unroll
    for (int ti = 0; ti < 4; ++ti)
        #pragma unroll
        for (int reg = 0; reg < 4; ++reg) {
            int gi = bm * 128 + wr + ti * 16 + q * 4 + reg;
            sA[ti * 4 + reg] = sq[gi];
            tA[ti * 4 + reg] = targets[gi];
        }
    float sB[4]; int tB[4];
    #pragma unroll
    for (int tj = 0; tj < 4; ++tj) {
        int gj = HALF + bn * 128 + wc + tj * 16 + c;
        sB[tj] = sq[gj];
        tB[tj] = targets[gj];
    }

    float rmax[16], rmin[16], cmax[4], cmin[4];
    #pragma unroll
    for (int i = 0; i < 16; ++i) { rmax[i] = NEG_INF; rmin[i] = POS_INF; }
    #pragma unroll
    for (int j = 0; j < 4; ++j)  { cmax[j] = NEG_INF; cmin[j] = POS_INF; }

    #pragma unroll
    for (int ti = 0; ti < 4; ++ti)
        #pragma unroll
        for (int tj = 0; tj < 4; ++tj)
            #pragma unroll
            for (int reg = 0; reg < 4; ++reg) {
                int ri = ti * 4 + reg;
                float dot = acc[ti][tj][reg];
                float d2  = fmaxf(sA[ri] + sB[tj] - 2.0f * dot, 0.0f);
                bool same = (tA[ri] == tB[tj]);
                if (same) {
                    rmax[ri] = fmaxf(rmax[ri], d2);
                    cmax[tj] = fmaxf(cmax[tj], d2);
                } else {
                    rmin[ri] = fminf(rmin[ri], d2);
                    cmin[tj] = fminf(cmin[tj], d2);
                }
            }

    // row reduce across the 16 cols held by lanes sharing q (xor 1,2,4,8)
    #pragma unroll
    for (int m = 1; m <= 8; m <<= 1)
        #pragma unroll
        for (int i = 0; i < 16; ++i) {
            rmax[i] = fmaxf(rmax[i], __shfl_xor(rmax[i], m, 64));
            rmin[i] = fminf(rmin[i], __shfl_xor(rmin[i], m, 64));
        }
    if (c == 0) {
        #pragma unroll
        for (int ti = 0; ti < 4; ++ti)
            #pragma unroll
            for (int reg = 0; reg < 4; ++reg) {
                int gi = bm * 128 + wr + ti * 16 + q * 4 + reg;
                atomicMax(&maxpos[gi], __float_as_int(rmax[ti * 4 + reg]));
                atomicMin(&minneg[gi], __float_as_int(rmin[ti * 4 + reg]));
            }
    }

    // col reduce across the 4 q-groups (xor 16, 32)
    #pragma unroll
    for (int m = 16; m <= 32; m <<= 1)
        #pragma unroll
        for (int j = 0; j < 4; ++j) {
            cmax[j] = fmaxf(cmax[j], __shfl_xor(cmax[j], m, 64));
            cmin[j] = fminf(cmin[j], __shfl_xor(cmin[j], m, 64));
        }
    if (q == 0) {
        #pragma unroll
        for (int tj = 0; tj < 4; ++tj) {
            int gj = HALF + bn * 128 + wc + tj * 16 + c;
            atomicMax(&maxpos[gj], __float_as_int(cmax[tj]));
            atomicMin(&minneg[gj], __float_as_int(cmin[tj]));
        }
    }
}

// ---------------------------------------------------------------------------
// final: dist_ap/dist_an, margin loss mean, correct count. Single block.
// ---------------------------------------------------------------------------
__global__ __launch_bounds__(256) void final_kernel(
        const int* __restrict__ maxpos, const int* __restrict__ minneg,
        float* __restrict__ out) {
    const int t = threadIdx.x;
    float sum = 0.0f;
    int cnt = 0;
    for (int i = t; i < N_TOTAL; i += 256) {
        float ap2 = __int_as_float(maxpos[i]);
        float an2 = __int_as_float(minneg[i]);
        float ap = sqrtf(fmaxf(ap2, 1e-12f));
        float an = sqrtf(fmaxf(an2, 1e-12f));
        sum += fmaxf(ap - an + MARGIN, 0.0f);
        cnt += (an >= ap) ? 1 : 0;
    }
    #pragma unroll
    for (int m = 1; m < 64; m <<= 1) {
        sum += __shfl_xor(sum, m, 64);
        cnt += __shfl_xor(cnt, m, 64);
    }
    __shared__ float ssum[4];
    __shared__ int   scnt[4];
    if ((t & 63) == 0) { ssum[t >> 6] = sum; scnt[t >> 6] = cnt; }
    __syncthreads();
    if (t == 0) {
        float S = ssum[0] + ssum[1] + ssum[2] + ssum[3];
        int   C = scnt[0] + scnt[1] + scnt[2] + scnt[3];
        out[0] = S / (float)N_TOTAL;
        out[1] = (float)C;
    }
}

extern "C" void kernel_launch(void* const* d_in, const int* in_sizes, int n_in,
                              void* d_out, int out_size, void* d_ws, size_t ws_size,
                              hipStream_t stream) {
    const float* X       = (const float*)d_in[0];   // [16384,128] fp32
    const int*   targets = (const int*)d_in[1];     // [16384] int32
    float* out = (float*)d_out;                     // [2]: loss, correct

    char* ws = (char*)d_ws;
    unsigned short* Xb = (unsigned short*)ws;                       // 4 MB bf16
    const size_t XB_BYTES = (size_t)N_TOTAL * FEAT * 2;
    float* sq     = (float*)(ws + XB_BYTES);                        // 64 KB
    int*   maxpos = (int*)(ws + XB_BYTES + 65536);                  // 64 KB
    int*   minneg = (int*)(ws + XB_BYTES + 2 * 65536);              // 64 KB

    prep_kernel <<<N_TOTAL, 128, 0, stream>>>(X, Xb, sq, maxpos, minneg);
    cross_kernel<<<dim3(64, 64), 256, 0, stream>>>(Xb, sq, targets, maxpos, minneg);
    final_kernel<<<1, 256, 0, stream>>>(maxpos, minneg, out);
}

// Round 3
// 131.108 us; speedup vs baseline: 1.3749x; 1.3749x over previous
//
#include <hip/hip_runtime.h>

#define N_TOTAL 16384
#define HALF    8192
#define FEAT    128
#define MARGIN  0.3f
#define NBINS   1024   // NUM_IDS=1000 <= 1024

typedef __attribute__((ext_vector_type(8))) short  short8v;   // 8 x bf16 (4 VGPRs)
typedef __attribute__((ext_vector_type(4))) float  float4v;   // 4 x f32 acc

__device__ __forceinline__ unsigned short f32_to_bf16_rne(float f) {
    unsigned u = __float_as_uint(f);
    u += 0x7FFFu + ((u >> 16) & 1u);
    return (unsigned short)(u >> 16);
}

// ---------------------------------------------------------------------------
// counting sort of each modality half by label
// ---------------------------------------------------------------------------
__global__ __launch_bounds__(256) void hist_kernel(
        const int* __restrict__ targets, int* __restrict__ hist) {
    int i = blockIdx.x * 256 + threadIdx.x;        // 0..16383
    int h = i >> 13;                               // modality half
    atomicAdd(&hist[(h << 10) + targets[i]], 1);
}

__global__ __launch_bounds__(1024) void scan_kernel(
        const int* __restrict__ hist, int* __restrict__ cursor) {
    const int h = blockIdx.x;                      // half 0/1
    const int t = threadIdx.x;                     // bin 0..1023
    const int lane = t & 63, wave = t >> 6;
    int x = hist[(h << 10) + t];
    const int orig = x;
    #pragma unroll
    for (int m = 1; m < 64; m <<= 1) {             // inclusive wave scan
        int v = __shfl_up(x, m, 64);
        if (lane >= m) x += v;
    }
    __shared__ int wsum[16], woff[16];
    if (lane == 63) wsum[wave] = x;
    __syncthreads();
    if (t == 0) {
        int s = 0;
        for (int w = 0; w < 16; ++w) { woff[w] = s; s += wsum[w]; }
    }
    __syncthreads();
    cursor[(h << 10) + t] = x + woff[wave] - orig; // exclusive prefix (bucket start)
}

__global__ __launch_bounds__(256) void scatter_kernel(
        const int* __restrict__ targets, int* __restrict__ cursor,
        int* __restrict__ perm, int* __restrict__ labs) {
    int i = blockIdx.x * 256 + threadIdx.x;        // 0..16383
    int h = i >> 13;
    int lbl = targets[i];
    int pos = atomicAdd(&cursor[(h << 10) + lbl], 1);
    int dst = (h << 13) + pos;                     // sorted position within its half
    perm[dst] = i;
    labs[dst] = lbl;
}

// ---------------------------------------------------------------------------
// prep: gather by perm, fp32 -> bf16, bf16 row norms, init max/min sentinels.
// One wave per sorted row; lane loads float2.
// ---------------------------------------------------------------------------
__global__ __launch_bounds__(256) void prep_kernel(
        const float* __restrict__ X, const int* __restrict__ perm,
        unsigned* __restrict__ Xb, float* __restrict__ sq,
        int* __restrict__ maxpos, int* __restrict__ minneg) {
    const int wave = threadIdx.x >> 6, lane = threadIdx.x & 63;
    const int r = blockIdx.x * 4 + wave;           // sorted row
    const int src = perm[r];
    const float2 xv = ((const float2*)(X + (size_t)src * FEAT))[lane];
    unsigned short h0 = f32_to_bf16_rne(xv.x);
    unsigned short h1 = f32_to_bf16_rne(xv.y);
    Xb[r * 64 + lane] = (unsigned)h0 | ((unsigned)h1 << 16);
    float x0 = __uint_as_float((unsigned)h0 << 16);
    float x1 = __uint_as_float((unsigned)h1 << 16);
    float p = x0 * x0 + x1 * x1;
    #pragma unroll
    for (int m = 1; m < 64; m <<= 1) p += __shfl_xor(p, m, 64);
    if (lane == 0) {
        sq[r] = p;
        maxpos[r] = (int)0xFF800000u;   // -inf
        minneg[r] = 0x7F800000;         // +inf
    }
}

// ---------------------------------------------------------------------------
// main: 128x128 tile of the 8192x8192 cross-modality block (sorted order).
// Fast path when A-rows' and B-cols' label ranges don't overlap (all pairs
// negative): min-only epilogue. Slow path (~5% of tiles): full select.
// ---------------------------------------------------------------------------
__global__ __launch_bounds__(256, 2) void cross_kernel(
        const unsigned short* __restrict__ Xb, const float* __restrict__ sq,
        const int* __restrict__ labs,
        int* __restrict__ maxpos, int* __restrict__ minneg) {
    __shared__ unsigned short As[128 * 128];
    __shared__ unsigned short Bs[128 * 128];
    const int bm = blockIdx.x, bn = blockIdx.y;
    const int t  = threadIdx.x;

    const unsigned short* Ag = Xb + (size_t)bm * 128 * FEAT;
    const unsigned short* Bg = Xb + (size_t)(HALF + bn * 128) * FEAT;
    #pragma unroll
    for (int p = 0; p < 8; ++p) {
        int idx = p * 256 + t;            // 16B chunk id, 0..2047
        int row = idx >> 4, ch = idx & 15;
        int sc  = ch ^ (row & 7);
        uint4 va = ((const uint4*)Ag)[idx];
        uint4 vb = ((const uint4*)Bg)[idx];
        *(uint4*)&As[row * 128 + sc * 8] = va;
        *(uint4*)&Bs[row * 128 + sc * 8] = vb;
    }
    __syncthreads();

    const int wave = t >> 6, lane = t & 63;
    const int q = lane >> 4, c = lane & 15;
    const int wr = (wave >> 1) * 64, wc = (wave & 1) * 64;

    float4v acc[4][4] = {};
    #pragma unroll
    for (int kk = 0; kk < 4; ++kk) {
        short8v af[4], bfr[4];
        #pragma unroll
        for (int ti = 0; ti < 4; ++ti) {
            int row = wr + ti * 16 + c;
            int sc  = (kk * 4 + q) ^ (row & 7);
            af[ti] = *(const short8v*)&As[row * 128 + sc * 8];
        }
        #pragma unroll
        for (int tj = 0; tj < 4; ++tj) {
            int row = wc + tj * 16 + c;
            int sc  = (kk * 4 + q) ^ (row & 7);
            bfr[tj] = *(const short8v*)&Bs[row * 128 + sc * 8];
        }
        #pragma unroll
        for (int ti = 0; ti < 4; ++ti)
            #pragma unroll
            for (int tj = 0; tj < 4; ++tj)
                acc[ti][tj] = __builtin_amdgcn_mfma_f32_16x16x32_bf16(
                    af[ti], bfr[tj], acc[ti][tj], 0, 0, 0);
    }

    // ---- epilogue: C layout col = lane&15 (=c), row = q*4 + reg
    const float NEG_INF = __int_as_float((int)0xFF800000u);
    const float POS_INF = __int_as_float(0x7F800000);

    const int aMin = labs[bm * 128], aMax = labs[bm * 128 + 127];
    const int bMn  = labs[HALF + bn * 128], bMx = labs[HALF + bn * 128 + 127];
    const bool overlap = (aMax >= bMn) && (bMx >= aMin);   // block-uniform

    float sA[16];
    #pragma unroll
    for (int ti = 0; ti < 4; ++ti)
        #pragma unroll
        for (int reg = 0; reg < 4; ++reg)
            sA[ti * 4 + reg] = sq[bm * 128 + wr + ti * 16 + q * 4 + reg];
    float sB[4];
    #pragma unroll
    for (int tj = 0; tj < 4; ++tj)
        sB[tj] = sq[HALF + bn * 128 + wc + tj * 16 + c];

    float rmin[16], cmin[4];
    #pragma unroll
    for (int i = 0; i < 16; ++i) rmin[i] = POS_INF;
    #pragma unroll
    for (int j = 0; j < 4; ++j)  cmin[j] = POS_INF;

    if (!overlap) {
        // ---- fast path: every pair is a negative
        #pragma unroll
        for (int ti = 0; ti < 4; ++ti)
            #pragma unroll
            for (int tj = 0; tj < 4; ++tj)
                #pragma unroll
                for (int reg = 0; reg < 4; ++reg) {
                    int ri = ti * 4 + reg;
                    float d2 = fmaf(acc[ti][tj][reg], -2.0f, sA[ri] + sB[tj]);
                    rmin[ri] = fminf(rmin[ri], d2);
                    cmin[tj] = fminf(cmin[tj], d2);
                }
        #pragma unroll
        for (int m = 1; m <= 8; m <<= 1)
            #pragma unroll
            for (int i = 0; i < 16; ++i)
                rmin[i] = fminf(rmin[i], __shfl_xor(rmin[i], m, 64));
        if (c == 0) {
            #pragma unroll
            for (int ti = 0; ti < 4; ++ti)
                #pragma unroll
                for (int reg = 0; reg < 4; ++reg)
                    atomicMin(&minneg[bm * 128 + wr + ti * 16 + q * 4 + reg],
                              __float_as_int(rmin[ti * 4 + reg]));
        }
        #pragma unroll
        for (int m = 16; m <= 32; m <<= 1)
            #pragma unroll
            for (int j = 0; j < 4; ++j)
                cmin[j] = fminf(cmin[j], __shfl_xor(cmin[j], m, 64));
        if (q == 0) {
            #pragma unroll
            for (int tj = 0; tj < 4; ++tj)
                atomicMin(&minneg[HALF + bn * 128 + wc + tj * 16 + c],
                          __float_as_int(cmin[tj]));
        }
    } else {
        // ---- slow path: labels may match
        float rmax[16], cmax[4];
        #pragma unroll
        for (int i = 0; i < 16; ++i) rmax[i] = NEG_INF;
        #pragma unroll
        for (int j = 0; j < 4; ++j)  cmax[j] = NEG_INF;

        int tA[16];
        #pragma unroll
        for (int ti = 0; ti < 4; ++ti)
            #pragma unroll
            for (int reg = 0; reg < 4; ++reg)
                tA[ti * 4 + reg] = labs[bm * 128 + wr + ti * 16 + q * 4 + reg];
        int tB[4];
        #pragma unroll
        for (int tj = 0; tj < 4; ++tj)
            tB[tj] = labs[HALF + bn * 128 + wc + tj * 16 + c];

        #pragma unroll
        for (int ti = 0; ti < 4; ++ti)
            #pragma unroll
            for (int tj = 0; tj < 4; ++tj) {
                #pragma unroll
                for (int reg = 0; reg < 4; ++reg) {
                    int ri = ti * 4 + reg;
                    float d2 = fmaf(acc[ti][tj][reg], -2.0f, sA[ri] + sB[tj]);
                    bool same = (tA[ri] == tB[tj]);
                    float posc = same ? d2 : NEG_INF;
                    float negc = same ? POS_INF : d2;
                    rmax[ri] = fmaxf(rmax[ri], posc);
                    cmax[tj] = fmaxf(cmax[tj], posc);
                    rmin[ri] = fminf(rmin[ri], negc);
                    cmin[tj] = fminf(cmin[tj], negc);
                }
            }
        #pragma unroll
        for (int m = 1; m <= 8; m <<= 1)
            #pragma unroll
            for (int i = 0; i < 16; ++i) {
                rmax[i] = fmaxf(rmax[i], __shfl_xor(rmax[i], m, 64));
                rmin[i] = fminf(rmin[i], __shfl_xor(rmin[i], m, 64));
            }
        if (c == 0) {
            #pragma unroll
            for (int ti = 0; ti < 4; ++ti)
                #pragma unroll
                for (int reg = 0; reg < 4; ++reg) {
                    int gi = bm * 128 + wr + ti * 16 + q * 4 + reg;
                    atomicMax(&maxpos[gi], __float_as_int(rmax[ti * 4 + reg]));
                    atomicMin(&minneg[gi], __float_as_int(rmin[ti * 4 + reg]));
                }
        }
        #pragma unroll
        for (int m = 16; m <= 32; m <<= 1)
            #pragma unroll
            for (int j = 0; j < 4; ++j) {
                cmax[j] = fmaxf(cmax[j], __shfl_xor(cmax[j], m, 64));
                cmin[j] = fminf(cmin[j], __shfl_xor(cmin[j], m, 64));
            }
        if (q == 0) {
            #pragma unroll
            for (int tj = 0; tj < 4; ++tj) {
                int gj = HALF + bn * 128 + wc + tj * 16 + c;
                atomicMax(&maxpos[gj], __float_as_int(cmax[tj]));
                atomicMin(&minneg[gj], __float_as_int(cmin[tj]));
            }
        }
    }
}

// ---------------------------------------------------------------------------
// final: per-row loss terms, accumulate into global scalars; then write out.
// ---------------------------------------------------------------------------
__global__ __launch_bounds__(256) void final_kernel(
        const int* __restrict__ maxpos, const int* __restrict__ minneg,
        float* __restrict__ accF, int* __restrict__ accI) {
    const int i = blockIdx.x * 256 + threadIdx.x;  // 64 blocks x 256 = 16384
    const int t = threadIdx.x;
    float ap = sqrtf(fmaxf(__int_as_float(maxpos[i]), 1e-12f));
    float an = sqrtf(fmaxf(__int_as_float(minneg[i]), 1e-12f));
    float term = fmaxf(ap - an + MARGIN, 0.0f);
    int cnt = (an >= ap) ? 1 : 0;
    #pragma unroll
    for (int m = 1; m < 64; m <<= 1) {
        term += __shfl_xor(term, m, 64);
        cnt  += __shfl_xor(cnt, m, 64);
    }
    __shared__ float sf[4];
    __shared__ int   si[4];
    if ((t & 63) == 0) { sf[t >> 6] = term; si[t >> 6] = cnt; }
    __syncthreads();
    if (t == 0) {
        atomicAdd(accF, sf[0] + sf[1] + sf[2] + sf[3]);
        atomicAdd(accI, si[0] + si[1] + si[2] + si[3]);
    }
}

__global__ void write_kernel(const float* __restrict__ accF,
                             const int* __restrict__ accI,
                             float* __restrict__ out) {
    out[0] = *accF / (float)N_TOTAL;
    out[1] = (float)(*accI);
}

extern "C" void kernel_launch(void* const* d_in, const int* in_sizes, int n_in,
                              void* d_out, int out_size, void* d_ws, size_t ws_size,
                              hipStream_t stream) {
    const float* X       = (const float*)d_in[0];   // [16384,128] fp32
    const int*   targets = (const int*)d_in[1];     // [16384] int32
    float* out = (float*)d_out;                     // [2]: loss, correct

    char* ws = (char*)d_ws;
    const size_t XB_BYTES = (size_t)N_TOTAL * FEAT * 2;              // 4 MB
    unsigned* Xb  = (unsigned*)ws;
    float* sq     = (float*)(ws + XB_BYTES);                         // 64 KB
    int* maxpos   = (int*)(ws + XB_BYTES + 1 * 65536);               // 64 KB
    int* minneg   = (int*)(ws + XB_BYTES + 2 * 65536);               // 64 KB
    int* perm     = (int*)(ws + XB_BYTES + 3 * 65536);               // 64 KB
    int* labs     = (int*)(ws + XB_BYTES + 4 * 65536);               // 64 KB
    int* hist     = (int*)(ws + XB_BYTES + 5 * 65536);               // 8 KB (2x1024)
    int* cursor   = hist + 2 * NBINS;                                // 8 KB
    float* accF   = (float*)(cursor + 2 * NBINS);
    int*   accI   = (int*)(accF + 1);

    // zero hist + cursor + accF/accI in one shot (cursor rewritten by scan anyway)
    hipMemsetAsync(hist, 0, 4 * NBINS * sizeof(int) + 8, stream);

    hist_kernel   <<<64, 256, 0, stream>>>(targets, hist);
    scan_kernel   <<<2, 1024, 0, stream>>>(hist, cursor);
    scatter_kernel<<<64, 256, 0, stream>>>(targets, cursor, perm, labs);
    prep_kernel   <<<4096, 256, 0, stream>>>(X, perm, Xb, sq, maxpos, minneg);
    cross_kernel  <<<dim3(64, 64), 256, 0, stream>>>(
        (const unsigned short*)Xb, sq, labs, maxpos, minneg);
    final_kernel  <<<64, 256, 0, stream>>>(maxpos, minneg, accF, accI);
    write_kernel  <<<1, 1, 0, stream>>>(accF, accI, out);
}